// Round 1
// baseline (2105.956 us; speedup 1.0000x reference)
//
#include <hip/hip_runtime.h>
#include <cstdint>
#include <cstddef>

#define DD 128
#define NHEAD 4
#define HC 32
#define LSTMH 256
#define ZG 1024
#define NCHUNK 10000

static inline int cdiv_(int a, int b) { return (a + b - 1) / b; }

__device__ __forceinline__ float sigm_(float x) { return 1.f / (1.f + __expf(-x)); }

// ---------------- input embedding + W_in GEMV (K=33) ----------------
__global__ __launch_bounds__(128) void embed_in(
    const int* __restrict__ labels, const int* __restrict__ types,
    const float* __restrict__ nf, const float* __restrict__ embL,
    const float* __restrict__ embT, const float* __restrict__ W,
    const float* __restrict__ b, float* __restrict__ x, int N) {
  int n = blockIdx.x;
  if (n >= N) return;
  int t = threadIdx.x;
  __shared__ float f[33];
  if (t < 16) f[t] = embL[labels[n] * 16 + t];
  else if (t < 32) f[t] = embT[types[n] * 16 + (t - 16)];
  else if (t == 32) f[32] = nf[n];
  __syncthreads();
  float acc = b[t];
#pragma unroll
  for (int k = 0; k < 33; ++k) acc += f[k] * W[k * DD + t];
  x[(size_t)n * DD + t] = acc;
}

// ---------------- CSR build ----------------
__global__ void count_deg(const int* __restrict__ ei, int* __restrict__ deg, int E_, int N_) {
  int i = blockIdx.x * 256 + threadIdx.x;
  if (i < E_) atomicAdd(&deg[ei[E_ + i]], 1);        // dst row
  else if (i < E_ + N_) atomicAdd(&deg[i - E_], 1);  // self loop
}

__global__ __launch_bounds__(256) void scan1(const int* __restrict__ deg, int* __restrict__ offs,
                                             int* __restrict__ partials, int N_) {
  __shared__ int buf[2][256];
  int tid = threadIdx.x;
  int i = blockIdx.x * 256 + tid;
  int v = (i < N_) ? deg[i] : 0;
  buf[0][tid] = v;
  __syncthreads();
  int cur = 0;
#pragma unroll
  for (int d = 1; d < 256; d <<= 1) {
    int xv = buf[cur][tid];
    if (tid >= d) xv += buf[cur][tid - d];
    buf[cur ^ 1][tid] = xv;
    cur ^= 1;
    __syncthreads();
  }
  int incl = buf[cur][tid];
  if (i < N_) offs[i] = incl - v;
  if (tid == 255) partials[blockIdx.x] = incl;
}

__global__ __launch_bounds__(256) void scan2(int* __restrict__ partials, int* __restrict__ offs,
                                             int nb, int N_) {
  __shared__ int buf[2][256];
  int tid = threadIdx.x;
  int v = (tid < nb) ? partials[tid] : 0;
  buf[0][tid] = v;
  __syncthreads();
  int cur = 0;
#pragma unroll
  for (int d = 1; d < 256; d <<= 1) {
    int xv = buf[cur][tid];
    if (tid >= d) xv += buf[cur][tid - d];
    buf[cur ^ 1][tid] = xv;
    cur ^= 1;
    __syncthreads();
  }
  int incl = buf[cur][tid];
  if (tid < nb) partials[tid] = incl - v;
  if (tid == 255) offs[N_] = incl;
}

__global__ void scan3(int* __restrict__ offs, const int* __restrict__ partials, int N_) {
  int i = blockIdx.x * 256 + threadIdx.x;
  if (i < N_) offs[i] += partials[blockIdx.x];
}

__global__ void fill_csr(const int* __restrict__ ei, const int* __restrict__ offs,
                         int* __restrict__ cursor, int* __restrict__ csr, int E_, int N_) {
  int i = blockIdx.x * 256 + threadIdx.x;
  int s, d;
  if (i < E_) { s = ei[i]; d = ei[E_ + i]; }
  else if (i < E_ + N_) { s = d = i - E_; }
  else return;
  int pos = offs[d] + atomicAdd(&cursor[d], 1);
  csr[pos] = s;
}

// ---------------- graph ranges ----------------
__global__ void graph_ranges(const int* __restrict__ bids, int* __restrict__ gstart,
                             float* __restrict__ invcnt, int N_, int G_) {
  int t = threadIdx.x;
  if (t <= G_) {
    int lo = 0, hi = N_;
    while (lo < hi) { int mid = (lo + hi) >> 1; if (bids[mid] < t) lo = mid + 1; else hi = mid; }
    gstart[t] = lo;
  }
  __syncthreads();
  if (t < G_) {
    int c = gstart[t + 1] - gstart[t];
    invcnt[t] = (c > 0) ? 1.f / (float)c : 0.f;
  }
}

// ---------------- generic tiled fp32 GEMM: C = A[N,K] @ B + bias ----------------
// TRANSB=false: B is [K,M] row-major. TRANSB=true: B is [M,K] row-major (C=A@B^T).
template <bool TRANSB>
__global__ __launch_bounds__(256) void gemm_f32(
    const float* __restrict__ A, const float* __restrict__ B,
    const float* __restrict__ bias, float* __restrict__ C, int N, int K, int M) {
  __shared__ __attribute__((aligned(16))) float As[16][68];
  __shared__ __attribute__((aligned(16))) float Bs[16][68];
  int tid = threadIdx.x;
  int tx = tid & 15, ty = tid >> 4;
  int rowBase = blockIdx.y * 64, colBase = blockIdx.x * 64;
  float acc[4][4] = {};
  for (int k0 = 0; k0 < K; k0 += 16) {
#pragma unroll
    for (int q = 0; q < 4; ++q) {
      int li = q * 256 + tid;
      int r = li >> 4, k = li & 15;
      int gr = rowBase + r, gk = k0 + k;
      As[k][r] = (gr < N && gk < K) ? A[(size_t)gr * K + gk] : 0.f;
    }
    if (!TRANSB) {
#pragma unroll
      for (int q = 0; q < 4; ++q) {
        int li = q * 256 + tid;
        int k = li >> 6, nn = li & 63;
        int gk = k0 + k, gc = colBase + nn;
        Bs[k][nn] = (gk < K && gc < M) ? B[(size_t)gk * M + gc] : 0.f;
      }
    } else {
#pragma unroll
      for (int q = 0; q < 4; ++q) {
        int li = q * 256 + tid;
        int r = li >> 4, k = li & 15;
        int gc = colBase + r, gk = k0 + k;
        Bs[k][r] = (gc < M && gk < K) ? B[(size_t)gc * K + gk] : 0.f;
      }
    }
    __syncthreads();
#pragma unroll
    for (int kk = 0; kk < 16; ++kk) {
      float4 a = *(const float4*)&As[kk][ty * 4];
      float4 b = *(const float4*)&Bs[kk][tx * 4];
      float av[4] = {a.x, a.y, a.z, a.w};
      float bv[4] = {b.x, b.y, b.z, b.w};
#pragma unroll
      for (int i = 0; i < 4; ++i)
#pragma unroll
        for (int j = 0; j < 4; ++j) acc[i][j] = fmaf(av[i], bv[j], acc[i][j]);
    }
    __syncthreads();
  }
#pragma unroll
  for (int i = 0; i < 4; ++i) {
    int gr = rowBase + ty * 4 + i;
    if (gr >= N) continue;
#pragma unroll
    for (int j = 0; j < 4; ++j) {
      int gc = colBase + tx * 4 + j;
      if (gc < M) C[(size_t)gr * M + gc] = acc[i][j] + bias[gc];
    }
  }
}

// ---------------- GATv2 aggregation: one wave per node, online softmax ----------------
__global__ __launch_bounds__(256) void gat_agg(
    const float* __restrict__ xl, const float* __restrict__ xr,
    const int* __restrict__ csr, const int* __restrict__ offs,
    const float* __restrict__ att, const float* __restrict__ bias,
    float* __restrict__ out, int N) {
  int wid = (blockIdx.x * 256 + threadIdx.x) >> 6;  // node = global wave id
  if (wid >= N) return;
  int lane = threadIdx.x & 63;
  int ch = lane * 2;
  int h = lane >> 4;
  float2 att2 = *(const float2*)&att[h * 32 + (ch & 31)];
  float2 xr2 = *(const float2*)&xr[(size_t)wid * DD + ch];
  float m = -1e30f, L = 0.f, a0 = 0.f, a1 = 0.f;
  int js = offs[wid], je = offs[wid + 1];
  for (int j = js; j < je; ++j) {
    int s = csr[j];
    float2 xj = *(const float2*)&xl[(size_t)s * DD + ch];
    float v0 = xr2.x + xj.x; v0 = v0 > 0.f ? v0 : 0.2f * v0;
    float v1 = xr2.y + xj.y; v1 = v1 > 0.f ? v1 : 0.2f * v1;
    float p = att2.x * v0 + att2.y * v1;
    p += __shfl_xor(p, 1); p += __shfl_xor(p, 2);
    p += __shfl_xor(p, 4); p += __shfl_xor(p, 8);
    float mn = fmaxf(m, p);
    float ea = __expf(p - mn);
    float es = __expf(m - mn);
    L = L * es + ea;
    a0 = a0 * es + ea * xj.x;
    a1 = a1 * es + ea * xj.y;
    m = mn;
  }
  float inv = 1.f / L;
  float2 o;
  o.x = a0 * inv + bias[ch];
  o.y = a1 * inv + bias[ch + 1];
  *(float2*)&out[(size_t)wid * DD + ch] = o;
}

// ---------------- GraphNorm ----------------
__global__ __launch_bounds__(128) void gn_stats(const float* __restrict__ x,
                                                const int* __restrict__ gstart,
                                                float* __restrict__ gsum, float* __restrict__ gsq) {
  int g = blockIdx.x;
  int ch = threadIdx.x;
  int st = gstart[g], en = gstart[g + 1];
  float s = 0.f, q = 0.f;
  for (int i = st; i < en; ++i) {
    float v = x[(size_t)i * DD + ch];
    s += v; q += v * v;
  }
  gsum[g * DD + ch] = s;
  gsq[g * DD + ch] = q;
}

template <bool ADDRES>
__global__ void gn_apply(float* __restrict__ x, const float* __restrict__ res,
                         const int* __restrict__ bids, const float* __restrict__ gsum,
                         const float* __restrict__ gsq, const float* __restrict__ invcnt,
                         const float* __restrict__ w, const float* __restrict__ b,
                         const float* __restrict__ ms, int N) {
  int idx = blockIdx.x * 256 + threadIdx.x;
  if (idx >= N * DD) return;
  int n = idx >> 7, ch = idx & 127;
  int g = bids[n];
  float ic = invcnt[g];
  float mean = gsum[g * DD + ch] * ic;
  float ex2 = gsq[g * DD + ch] * ic;
  float mm = mean * ms[ch];
  float var = ex2 - mm * (2.f * mean - mm);
  float v = (x[idx] - mm) * rsqrtf(var + 1e-5f) * w[ch] + b[ch];
  if (ADDRES) v += res[idx];
  x[idx] = v > 0.f ? v : (__expf(v) - 1.f);
}

// ---------------- LSTM / bias ----------------
__global__ void bias_sum(const float* a1, const float* b1, const float* a2, const float* b2,
                         float* o1, float* o2) {
  int t = blockIdx.x * 256 + threadIdx.x;
  if (t < ZG) { o1[t] = a1[t] + b1[t]; o2[t] = a2[t] + b2[t]; }
}

__global__ void lstm_act(const float* __restrict__ gates, float* __restrict__ h, int rows) {
  int idx = blockIdx.x * 256 + threadIdx.x;
  if (idx >= rows * LSTMH) return;
  int n = idx >> 8, j = idx & 255;
  const float* g = gates + (size_t)n * ZG;
  float iv = g[j], gv = g[512 + j], ov = g[768 + j];
  float c = sigm_(iv) * tanhf(gv);
  h[idx] = sigm_(ov) * tanhf(c);
}

// ---------------- LayerNorm + mean pool ----------------
__global__ __launch_bounds__(256) void ln_pool(const float* __restrict__ h2,
                                               const int* __restrict__ bids,
                                               const float* __restrict__ lnw,
                                               const float* __restrict__ lnb,
                                               const float* __restrict__ invcnt,
                                               float* __restrict__ pooled, int base, int rows) {
  int n = blockIdx.x;
  if (n >= rows) return;
  int t = threadIdx.x;
  float v = h2[(size_t)n * LSTMH + t];
  float s = v, q = v * v;
#pragma unroll
  for (int d = 1; d < 64; d <<= 1) { s += __shfl_xor(s, d); q += __shfl_xor(q, d); }
  __shared__ float ss[4], qq[4];
  int w = t >> 6;
  if ((t & 63) == 0) { ss[w] = s; qq[w] = q; }
  __syncthreads();
  float S = ss[0] + ss[1] + ss[2] + ss[3];
  float Q = qq[0] + qq[1] + qq[2] + qq[3];
  float mu = S * (1.f / 256.f);
  float var = Q * (1.f / 256.f) - mu * mu;
  float hn = lnw[t] * (v - mu) * rsqrtf(var + 1e-5f) + lnb[t];
  int g = bids[base + n];
  atomicAdd(&pooled[g * LSTMH + t], hn * invcnt[g]);
}

// ---------------- FC + log_softmax ----------------
__global__ __launch_bounds__(64) void fc_lsm(const float* __restrict__ pooled,
                                             const float* __restrict__ W,
                                             const float* __restrict__ b, float* __restrict__ out) {
  int g = blockIdx.x;
  int t = threadIdx.x;
  float l0 = 0.f, l1 = 0.f, l2 = 0.f, l3 = 0.f;
  for (int k = t; k < LSTMH; k += 64) {
    float p = pooled[g * LSTMH + k];
    l0 += p * W[k * 4 + 0];
    l1 += p * W[k * 4 + 1];
    l2 += p * W[k * 4 + 2];
    l3 += p * W[k * 4 + 3];
  }
#pragma unroll
  for (int d = 1; d < 64; d <<= 1) {
    l0 += __shfl_xor(l0, d); l1 += __shfl_xor(l1, d);
    l2 += __shfl_xor(l2, d); l3 += __shfl_xor(l3, d);
  }
  if (t == 0) {
    float z[4] = {l0 + b[0], l1 + b[1], l2 + b[2], l3 + b[3]};
    float mx = fmaxf(fmaxf(z[0], z[1]), fmaxf(z[2], z[3]));
    float sum = __expf(z[0] - mx) + __expf(z[1] - mx) + __expf(z[2] - mx) + __expf(z[3] - mx);
    float ls = logf(sum);
#pragma unroll
    for (int o = 0; o < 4; ++o) out[g * 4 + o] = z[o] - mx - ls;
  }
}

// ---------------- host launch ----------------
extern "C" void kernel_launch(void* const* d_in, const int* in_sizes, int n_in,
                              void* d_out, int out_size, void* d_ws, size_t ws_size,
                              hipStream_t stream) {
  const int* node_labels = (const int*)d_in[0];
  const int* node_types = (const int*)d_in[1];
  const float* node_feat = (const float*)d_in[2];
  const int* edge_index = (const int*)d_in[3];
  const int* batch_ids = (const int*)d_in[4];
  const float* emb_label = (const float*)d_in[5];
  const float* emb_type = (const float*)d_in[6];
  const float* W_in = (const float*)d_in[7];
  const float* b_in = (const float*)d_in[8];
  const float* g1_Wl = (const float*)d_in[9];
  const float* g1_bl = (const float*)d_in[10];
  const float* g1_Wr = (const float*)d_in[11];
  const float* g1_br = (const float*)d_in[12];
  const float* g1_att = (const float*)d_in[13];
  const float* g1_bias = (const float*)d_in[14];
  const float* gn1_w = (const float*)d_in[15];
  const float* gn1_b = (const float*)d_in[16];
  const float* gn1_ms = (const float*)d_in[17];
  const float* g2_Wl = (const float*)d_in[18];
  const float* g2_bl = (const float*)d_in[19];
  const float* g2_Wr = (const float*)d_in[20];
  const float* g2_br = (const float*)d_in[21];
  const float* g2_att = (const float*)d_in[22];
  const float* g2_bias = (const float*)d_in[23];
  const float* gn2_w = (const float*)d_in[24];
  const float* gn2_b = (const float*)d_in[25];
  const float* gn2_ms = (const float*)d_in[26];
  const float* W_res = (const float*)d_in[27];
  const float* b_res = (const float*)d_in[28];
  const float* l1_Wih = (const float*)d_in[29];
  const float* l1_bih = (const float*)d_in[31];
  const float* l1_bhh = (const float*)d_in[32];
  const float* l2_Wih = (const float*)d_in[33];
  const float* l2_bih = (const float*)d_in[35];
  const float* l2_bhh = (const float*)d_in[36];
  const float* ln_w = (const float*)d_in[37];
  const float* ln_b = (const float*)d_in[38];
  const float* fc_W = (const float*)d_in[39];
  const float* fc_b = (const float*)d_in[40];
  float* out = (float*)d_out;

  const int N = in_sizes[0];
  const int E = in_sizes[3] / 2;
  const int G = out_size / 4;
  const int ET = E + N;

  // workspace layout
  char* wsb = (char*)d_ws;
  size_t off = 0;
  auto alloc = [&](size_t bytes) -> void* {
    void* p = (void*)(wsb + off);
    off = (off + bytes + 255) & ~(size_t)255;
    return p;
  };
  float* xA = (float*)alloc((size_t)N * DD * 4);      // x -> gat2 out -> x2
  int* deg = (int*)alloc((size_t)N * 4);
  int* offs = (int*)alloc((size_t)(N + 1) * 4);
  int* cursor = (int*)alloc((size_t)N * 4);
  int* partials = (int*)alloc(1024);
  int* csr = (int*)alloc((size_t)ET * 4);
  int* gstart = (int*)alloc((size_t)(G + 1) * 4);
  float* invcnt = (float*)alloc((size_t)G * 4);
  float* gsum = (float*)alloc((size_t)G * DD * 4);
  float* gsq = (float*)alloc((size_t)G * DD * 4);
  float* pooled = (float*)alloc((size_t)G * LSTMH * 4);
  float* bsum1 = (float*)alloc(ZG * 4);
  float* bsum2 = (float*)alloc(ZG * 4);
  size_t gatR = 4ull * N * DD * 4;
  size_t lstmR = (size_t)NCHUNK * (ZG + LSTMH + LSTMH) * 4;
  float* R = (float*)alloc(gatR > lstmR ? gatR : lstmR);
  (void)ws_size; (void)n_in;

  float* xl = R;
  float* xr = R + (size_t)N * DD;
  float* x1 = R + 2ull * N * DD;
  float* res = R + 3ull * N * DD;
  float* gates = R;
  float* h1c = R + (size_t)NCHUNK * ZG;
  float* h2c = h1c + (size_t)NCHUNK * LSTMH;

  hipMemsetAsync(deg, 0, (size_t)N * 4, stream);
  hipMemsetAsync(cursor, 0, (size_t)N * 4, stream);
  hipMemsetAsync(pooled, 0, (size_t)G * LSTMH * 4, stream);

  bias_sum<<<cdiv_(ZG, 256), 256, 0, stream>>>(l1_bih, l1_bhh, l2_bih, l2_bhh, bsum1, bsum2);
  graph_ranges<<<1, 128, 0, stream>>>(batch_ids, gstart, invcnt, N, G);
  embed_in<<<N, 128, 0, stream>>>(node_labels, node_types, node_feat, emb_label, emb_type,
                                  W_in, b_in, xA, N);

  // CSR by dst
  count_deg<<<cdiv_(ET, 256), 256, 0, stream>>>(edge_index, deg, E, N);
  int nb1 = cdiv_(N, 256);
  scan1<<<nb1, 256, 0, stream>>>(deg, offs, partials, N);
  scan2<<<1, 256, 0, stream>>>(partials, offs, nb1, N);
  scan3<<<nb1, 256, 0, stream>>>(offs, partials, N);
  fill_csr<<<cdiv_(ET, 256), 256, 0, stream>>>(edge_index, offs, cursor, csr, E, N);

  dim3 gemmB(256);
  // ---- GAT layer 1 ----
  gemm_f32<false><<<dim3(DD / 64, cdiv_(N, 64)), gemmB, 0, stream>>>(xA, g1_Wl, g1_bl, xl, N, DD, DD);
  gemm_f32<false><<<dim3(DD / 64, cdiv_(N, 64)), gemmB, 0, stream>>>(xA, g1_Wr, g1_br, xr, N, DD, DD);
  gat_agg<<<cdiv_(N, 4), 256, 0, stream>>>(xl, xr, csr, offs, g1_att, g1_bias, x1, N);
  gn_stats<<<G, 128, 0, stream>>>(x1, gstart, gsum, gsq);
  gn_apply<false><<<cdiv_(N * DD, 256), 256, 0, stream>>>(x1, nullptr, batch_ids, gsum, gsq,
                                                          invcnt, gn1_w, gn1_b, gn1_ms, N);
  // ---- GAT layer 2 + residual ----
  gemm_f32<false><<<dim3(DD / 64, cdiv_(N, 64)), gemmB, 0, stream>>>(x1, g2_Wl, g2_bl, xl, N, DD, DD);
  gemm_f32<false><<<dim3(DD / 64, cdiv_(N, 64)), gemmB, 0, stream>>>(x1, g2_Wr, g2_br, xr, N, DD, DD);
  gemm_f32<false><<<dim3(DD / 64, cdiv_(N, 64)), gemmB, 0, stream>>>(x1, W_res, b_res, res, N, DD, DD);
  gat_agg<<<cdiv_(N, 4), 256, 0, stream>>>(xl, xr, csr, offs, g2_att, g2_bias, xA, N);
  gn_stats<<<G, 128, 0, stream>>>(xA, gstart, gsum, gsq);
  gn_apply<true><<<cdiv_(N * DD, 256), 256, 0, stream>>>(xA, res, batch_ids, gsum, gsq,
                                                         invcnt, gn2_w, gn2_b, gn2_ms, N);
  // ---- LSTM x2 + LN + pool (chunked over rows) ----
  for (int base = 0; base < N; base += NCHUNK) {
    int rows = N - base < NCHUNK ? N - base : NCHUNK;
    gemm_f32<true><<<dim3(ZG / 64, cdiv_(rows, 64)), gemmB, 0, stream>>>(
        xA + (size_t)base * DD, l1_Wih, bsum1, gates, rows, DD, ZG);
    lstm_act<<<cdiv_(rows * LSTMH, 256), 256, 0, stream>>>(gates, h1c, rows);
    gemm_f32<true><<<dim3(ZG / 64, cdiv_(rows, 64)), gemmB, 0, stream>>>(
        h1c, l2_Wih, bsum2, gates, rows, LSTMH, ZG);
    lstm_act<<<cdiv_(rows * LSTMH, 256), 256, 0, stream>>>(gates, h2c, rows);
    ln_pool<<<rows, 256, 0, stream>>>(h2c, batch_ids, ln_w, ln_b, invcnt, pooled, base, rows);
  }
  fc_lsm<<<G, 64, 0, stream>>>(pooled, fc_W, fc_b, out);
}

// Round 2
// 1062.224 us; speedup vs baseline: 1.9826x; 1.9826x over previous
//
#include <hip/hip_runtime.h>
#include <cstdint>
#include <cstddef>

#define DD 128
#define LSTMH 256
#define ZG 1024
#define NCHUNK 10000

typedef __attribute__((ext_vector_type(8))) short short8v;
typedef __attribute__((ext_vector_type(4))) float float4v;

static inline int cdiv_(int a, int b) { return (a + b - 1) / b; }

__device__ __forceinline__ float sigm_(float x) { return 1.f / (1.f + __expf(-x)); }

__device__ __forceinline__ unsigned short f2bf(float f) {
  uint32_t u = __float_as_uint(f);
  u += 0x7fffu + ((u >> 16) & 1u);
  return (unsigned short)(u >> 16);
}

// ---------------- weight conversion ----------------
__global__ void cvt_direct(const float* __restrict__ W, unsigned short* __restrict__ o, int n) {
  int i = blockIdx.x * 256 + threadIdx.x;
  if (i < n) o[i] = f2bf(W[i]);
}

// W[K][M] row-major -> o[M][K] bf16 (B' n-major layout)
__global__ void cvt_transpose(const float* __restrict__ W, unsigned short* __restrict__ o,
                              int K, int M) {
  int i = blockIdx.x * 256 + threadIdx.x;
  if (i >= K * M) return;
  int m = i / K, k = i - m * K;
  o[i] = f2bf(W[(size_t)k * M + m]);
}

// ---------------- input embedding + W_in GEMV (K=33) -> bf16 ----------------
__global__ __launch_bounds__(128) void embed_in(
    const int* __restrict__ labels, const int* __restrict__ types,
    const float* __restrict__ nf, const float* __restrict__ embL,
    const float* __restrict__ embT, const float* __restrict__ W,
    const float* __restrict__ b, unsigned short* __restrict__ x, int N) {
  int n = blockIdx.x;
  if (n >= N) return;
  int t = threadIdx.x;
  __shared__ float f[33];
  if (t < 16) f[t] = embL[labels[n] * 16 + t];
  else if (t < 32) f[t] = embT[types[n] * 16 + (t - 16)];
  else if (t == 32) f[32] = nf[n];
  __syncthreads();
  float acc = b[t];
#pragma unroll
  for (int k = 0; k < 33; ++k) acc += f[k] * W[k * DD + t];
  x[(size_t)n * DD + t] = f2bf(acc);
}

// ---------------- CSR build ----------------
__global__ void count_deg(const int* __restrict__ ei, int* __restrict__ deg, int E_, int N_) {
  int i = blockIdx.x * 256 + threadIdx.x;
  if (i < E_) atomicAdd(&deg[ei[E_ + i]], 1);
  else if (i < E_ + N_) atomicAdd(&deg[i - E_], 1);
}

__global__ __launch_bounds__(256) void scan1(const int* __restrict__ deg, int* __restrict__ offs,
                                             int* __restrict__ partials, int N_) {
  __shared__ int buf[2][256];
  int tid = threadIdx.x;
  int i = blockIdx.x * 256 + tid;
  int v = (i < N_) ? deg[i] : 0;
  buf[0][tid] = v;
  __syncthreads();
  int cur = 0;
#pragma unroll
  for (int d = 1; d < 256; d <<= 1) {
    int xv = buf[cur][tid];
    if (tid >= d) xv += buf[cur][tid - d];
    buf[cur ^ 1][tid] = xv;
    cur ^= 1;
    __syncthreads();
  }
  int incl = buf[cur][tid];
  if (i < N_) offs[i] = incl - v;
  if (tid == 255) partials[blockIdx.x] = incl;
}

__global__ __launch_bounds__(256) void scan2(int* __restrict__ partials, int* __restrict__ offs,
                                             int nb, int N_) {
  __shared__ int buf[2][256];
  int tid = threadIdx.x;
  int v = (tid < nb) ? partials[tid] : 0;
  buf[0][tid] = v;
  __syncthreads();
  int cur = 0;
#pragma unroll
  for (int d = 1; d < 256; d <<= 1) {
    int xv = buf[cur][tid];
    if (tid >= d) xv += buf[cur][tid - d];
    buf[cur ^ 1][tid] = xv;
    cur ^= 1;
    __syncthreads();
  }
  int incl = buf[cur][tid];
  if (tid < nb) partials[tid] = incl - v;
  if (tid == 255) offs[N_] = incl;
}

__global__ void scan3(int* __restrict__ offs, const int* __restrict__ partials, int N_) {
  int i = blockIdx.x * 256 + threadIdx.x;
  if (i < N_) offs[i] += partials[blockIdx.x];
}

__global__ void fill_csr(const int* __restrict__ ei, const int* __restrict__ offs,
                         int* __restrict__ cursor, int* __restrict__ csr, int E_, int N_) {
  int i = blockIdx.x * 256 + threadIdx.x;
  int s, d;
  if (i < E_) { s = ei[i]; d = ei[E_ + i]; }
  else if (i < E_ + N_) { s = d = i - E_; }
  else return;
  int pos = offs[d] + atomicAdd(&cursor[d], 1);
  csr[pos] = s;
}

// ---------------- graph ranges ----------------
__global__ void graph_ranges(const int* __restrict__ bids, int* __restrict__ gstart,
                             float* __restrict__ invcnt, int N_, int G_) {
  int t = threadIdx.x;
  if (t <= G_) {
    int lo = 0, hi = N_;
    while (lo < hi) { int mid = (lo + hi) >> 1; if (bids[mid] < t) lo = mid + 1; else hi = mid; }
    gstart[t] = lo;
  }
  __syncthreads();
  if (t < G_) {
    int c = gstart[t + 1] - gstart[t];
    invcnt[t] = (c > 0) ? 1.f / (float)c : 0.f;
  }
}

// ---------------- bf16 MFMA GEMM: C[M,Ncols] f32 = A[M,K]bf16 @ B'[Ncols,K]bf16^T + bias
// grid (Ncols/128, cdiv(M,128)), block 256 (4 waves, 2x2, each 64x64 output)
__global__ __launch_bounds__(256) void gemm_bf16(
    const unsigned short* __restrict__ A, const unsigned short* __restrict__ Bp,
    const float* __restrict__ bias, float* __restrict__ C, int M, int K, int Ncols) {
  // row stride 40 ushorts = 80B (16B aligned); per row, group-interleaved k layout:
  // bytes [16g..16g+8) = k in [4g,4g+4), bytes [16g+8..16g+16) = k in [16+4g,16+4g+4)
  __shared__ unsigned short As[128 * 40];
  __shared__ unsigned short Bs[128 * 40];
  int tid = threadIdx.x;
  int lane = tid & 63;
  int wid = tid >> 6;
  int rowBase = blockIdx.y * 128, colBase = blockIdx.x * 128;
  int wr = (wid >> 1) * 64, wc = (wid & 1) * 64;
  int fr = lane & 15, fg = lane >> 4;
  float4v acc[4][4];
#pragma unroll
  for (int i = 0; i < 4; ++i)
#pragma unroll
    for (int j = 0; j < 4; ++j) acc[i][j] = (float4v){0.f, 0.f, 0.f, 0.f};

  int sr = tid >> 2;  // staging row 0..63
  int sc = tid & 3;   // 8-elem k chunk
  int off_lo = (sc < 2) ? 32 * sc : 32 * sc - 56;  // byte offset of lo-4 within row

  for (int k0 = 0; k0 < K; k0 += 32) {
#pragma unroll
    for (int it = 0; it < 2; ++it) {
      int r = it * 64 + sr;
      uint4 va = make_uint4(0u, 0u, 0u, 0u);
      if (rowBase + r < M)
        va = *(const uint4*)(A + (size_t)(rowBase + r) * K + k0 + sc * 8);
      char* arow = (char*)(As + r * 40);
      *(uint2*)(arow + off_lo) = make_uint2(va.x, va.y);
      *(uint2*)(arow + off_lo + 16) = make_uint2(va.z, va.w);
      uint4 vb = *(const uint4*)(Bp + (size_t)(colBase + r) * K + k0 + sc * 8);
      char* brow = (char*)(Bs + r * 40);
      *(uint2*)(brow + off_lo) = make_uint2(vb.x, vb.y);
      *(uint2*)(brow + off_lo + 16) = make_uint2(vb.z, vb.w);
    }
    __syncthreads();
    short8v af[4], bfv[4];
#pragma unroll
    for (int i = 0; i < 4; ++i)
      af[i] = *(const short8v*)((const char*)As + (wr + 16 * i + fr) * 80 + fg * 16);
#pragma unroll
    for (int j = 0; j < 4; ++j)
      bfv[j] = *(const short8v*)((const char*)Bs + (wc + 16 * j + fr) * 80 + fg * 16);
#pragma unroll
    for (int i = 0; i < 4; ++i)
#pragma unroll
      for (int j = 0; j < 4; ++j)
        acc[i][j] = __builtin_amdgcn_mfma_f32_16x16x32_bf16(af[i], bfv[j], acc[i][j], 0, 0, 0);
    __syncthreads();
  }
#pragma unroll
  for (int j = 0; j < 4; ++j) {
    int gc = colBase + wc + 16 * j + fr;
    float bv = bias[gc];
#pragma unroll
    for (int i = 0; i < 4; ++i) {
      int gr0 = rowBase + wr + 16 * i + fg * 4;
#pragma unroll
      for (int rg = 0; rg < 4; ++rg) {
        int gr = gr0 + rg;
        if (gr < M) C[(size_t)gr * Ncols + gc] = acc[i][j][rg] + bv;
      }
    }
  }
}

// ---------------- GATv2 aggregation: one wave per node, online softmax ----------------
__global__ __launch_bounds__(256) void gat_agg(
    const float* __restrict__ xl, const float* __restrict__ xr,
    const int* __restrict__ csr, const int* __restrict__ offs,
    const float* __restrict__ att, const float* __restrict__ bias,
    float* __restrict__ out, int N) {
  int wid = (blockIdx.x * 256 + threadIdx.x) >> 6;
  if (wid >= N) return;
  int lane = threadIdx.x & 63;
  int ch = lane * 2;
  int h = lane >> 4;
  float2 att2 = *(const float2*)&att[h * 32 + (ch & 31)];
  float2 xr2 = *(const float2*)&xr[(size_t)wid * DD + ch];
  float m = -1e30f, L = 0.f, a0 = 0.f, a1 = 0.f;
  int js = offs[wid], je = offs[wid + 1];
  for (int j = js; j < je; ++j) {
    int s = csr[j];
    float2 xj = *(const float2*)&xl[(size_t)s * DD + ch];
    float v0 = xr2.x + xj.x; v0 = v0 > 0.f ? v0 : 0.2f * v0;
    float v1 = xr2.y + xj.y; v1 = v1 > 0.f ? v1 : 0.2f * v1;
    float p = att2.x * v0 + att2.y * v1;
    p += __shfl_xor(p, 1); p += __shfl_xor(p, 2);
    p += __shfl_xor(p, 4); p += __shfl_xor(p, 8);
    float mn = fmaxf(m, p);
    float ea = __expf(p - mn);
    float es = __expf(m - mn);
    L = L * es + ea;
    a0 = a0 * es + ea * xj.x;
    a1 = a1 * es + ea * xj.y;
    m = mn;
  }
  float inv = 1.f / L;
  float2 o;
  o.x = a0 * inv + bias[ch];
  o.y = a1 * inv + bias[ch + 1];
  *(float2*)&out[(size_t)wid * DD + ch] = o;
}

// ---------------- GraphNorm stats: chunked, atomic flush on graph change ----------------
__global__ __launch_bounds__(256) void gn_stats2(const float* __restrict__ x,
                                                 const int* __restrict__ bids,
                                                 float* __restrict__ gsum,
                                                 float* __restrict__ gsq, int N) {
  int base = blockIdx.x * 128;
  int ch = threadIdx.x & 127;
  int sub = threadIdx.x >> 7;
  int end = base + 128 < N ? base + 128 : N;
  int curg = -1;
  float s = 0.f, q = 0.f;
  for (int r = base + sub; r < end; r += 2) {
    int g = bids[r];
    if (g != curg) {
      if (curg >= 0) {
        atomicAdd(&gsum[curg * DD + ch], s);
        atomicAdd(&gsq[curg * DD + ch], q);
      }
      curg = g; s = 0.f; q = 0.f;
    }
    float v = x[(size_t)r * DD + ch];
    s += v; q += v * v;
  }
  if (curg >= 0) {
    atomicAdd(&gsum[curg * DD + ch], s);
    atomicAdd(&gsq[curg * DD + ch], q);
  }
}

// ---------------- GraphNorm apply + ELU (+residual) -> bf16 ----------------
template <bool ADDRES>
__global__ void gn_apply(const float* __restrict__ xin, unsigned short* __restrict__ xout,
                         const float* __restrict__ res, const int* __restrict__ bids,
                         const float* __restrict__ gsum, const float* __restrict__ gsq,
                         const float* __restrict__ invcnt, const float* __restrict__ w,
                         const float* __restrict__ b, const float* __restrict__ ms, int N) {
  int idx = blockIdx.x * 256 + threadIdx.x;
  if (idx >= N * DD) return;
  int n = idx >> 7, ch = idx & 127;
  int g = bids[n];
  float ic = invcnt[g];
  float mean = gsum[g * DD + ch] * ic;
  float ex2 = gsq[g * DD + ch] * ic;
  float mm = mean * ms[ch];
  float var = ex2 - mm * (2.f * mean - mm);
  float v = (xin[idx] - mm) * rsqrtf(var + 1e-5f) * w[ch] + b[ch];
  if (ADDRES) v += res[idx];
  v = v > 0.f ? v : (__expf(v) - 1.f);
  xout[idx] = f2bf(v);
}

// ---------------- LSTM / bias ----------------
__global__ void bias_sum(const float* a1, const float* b1, const float* a2, const float* b2,
                         float* o1, float* o2) {
  int t = blockIdx.x * 256 + threadIdx.x;
  if (t < ZG) { o1[t] = a1[t] + b1[t]; o2[t] = a2[t] + b2[t]; }
}

__global__ void lstm_act_bf(const float* __restrict__ gates, unsigned short* __restrict__ h,
                            int rows) {
  int idx = blockIdx.x * 256 + threadIdx.x;
  if (idx >= rows * LSTMH) return;
  int n = idx >> 8, j = idx & 255;
  const float* g = gates + (size_t)n * ZG;
  float iv = g[j], gv = g[512 + j], ov = g[768 + j];
  float c = sigm_(iv) * tanhf(gv);
  h[idx] = f2bf(sigm_(ov) * tanhf(c));
}

__global__ void lstm_act_f(const float* __restrict__ gates, float* __restrict__ h, int rows) {
  int idx = blockIdx.x * 256 + threadIdx.x;
  if (idx >= rows * LSTMH) return;
  int n = idx >> 8, j = idx & 255;
  const float* g = gates + (size_t)n * ZG;
  float iv = g[j], gv = g[512 + j], ov = g[768 + j];
  float c = sigm_(iv) * tanhf(gv);
  h[idx] = sigm_(ov) * tanhf(c);
}

// ---------------- LayerNorm + mean pool ----------------
__global__ __launch_bounds__(256) void ln_pool(const float* __restrict__ h2,
                                               const int* __restrict__ bids,
                                               const float* __restrict__ lnw,
                                               const float* __restrict__ lnb,
                                               const float* __restrict__ invcnt,
                                               float* __restrict__ pooled, int base, int rows) {
  int n = blockIdx.x;
  if (n >= rows) return;
  int t = threadIdx.x;
  float v = h2[(size_t)n * LSTMH + t];
  float s = v, q = v * v;
#pragma unroll
  for (int d = 1; d < 64; d <<= 1) { s += __shfl_xor(s, d); q += __shfl_xor(q, d); }
  __shared__ float ss[4], qq[4];
  int w = t >> 6;
  if ((t & 63) == 0) { ss[w] = s; qq[w] = q; }
  __syncthreads();
  float S = ss[0] + ss[1] + ss[2] + ss[3];
  float Q = qq[0] + qq[1] + qq[2] + qq[3];
  float mu = S * (1.f / 256.f);
  float var = Q * (1.f / 256.f) - mu * mu;
  float hn = lnw[t] * (v - mu) * rsqrtf(var + 1e-5f) + lnb[t];
  int g = bids[base + n];
  atomicAdd(&pooled[g * LSTMH + t], hn * invcnt[g]);
}

// ---------------- FC + log_softmax ----------------
__global__ __launch_bounds__(64) void fc_lsm(const float* __restrict__ pooled,
                                             const float* __restrict__ W,
                                             const float* __restrict__ b, float* __restrict__ out) {
  int g = blockIdx.x;
  int t = threadIdx.x;
  float l0 = 0.f, l1 = 0.f, l2 = 0.f, l3 = 0.f;
  for (int k = t; k < LSTMH; k += 64) {
    float p = pooled[g * LSTMH + k];
    l0 += p * W[k * 4 + 0];
    l1 += p * W[k * 4 + 1];
    l2 += p * W[k * 4 + 2];
    l3 += p * W[k * 4 + 3];
  }
#pragma unroll
  for (int d = 1; d < 64; d <<= 1) {
    l0 += __shfl_xor(l0, d); l1 += __shfl_xor(l1, d);
    l2 += __shfl_xor(l2, d); l3 += __shfl_xor(l3, d);
  }
  if (t == 0) {
    float z[4] = {l0 + b[0], l1 + b[1], l2 + b[2], l3 + b[3]};
    float mx = fmaxf(fmaxf(z[0], z[1]), fmaxf(z[2], z[3]));
    float sum = __expf(z[0] - mx) + __expf(z[1] - mx) + __expf(z[2] - mx) + __expf(z[3] - mx);
    float ls = logf(sum);
#pragma unroll
    for (int o = 0; o < 4; ++o) out[g * 4 + o] = z[o] - mx - ls;
  }
}

// ---------------- host launch ----------------
extern "C" void kernel_launch(void* const* d_in, const int* in_sizes, int n_in,
                              void* d_out, int out_size, void* d_ws, size_t ws_size,
                              hipStream_t stream) {
  const int* node_labels = (const int*)d_in[0];
  const int* node_types = (const int*)d_in[1];
  const float* node_feat = (const float*)d_in[2];
  const int* edge_index = (const int*)d_in[3];
  const int* batch_ids = (const int*)d_in[4];
  const float* emb_label = (const float*)d_in[5];
  const float* emb_type = (const float*)d_in[6];
  const float* W_in = (const float*)d_in[7];
  const float* b_in = (const float*)d_in[8];
  const float* g1_Wl = (const float*)d_in[9];
  const float* g1_bl = (const float*)d_in[10];
  const float* g1_Wr = (const float*)d_in[11];
  const float* g1_br = (const float*)d_in[12];
  const float* g1_att = (const float*)d_in[13];
  const float* g1_bias = (const float*)d_in[14];
  const float* gn1_w = (const float*)d_in[15];
  const float* gn1_b = (const float*)d_in[16];
  const float* gn1_ms = (const float*)d_in[17];
  const float* g2_Wl = (const float*)d_in[18];
  const float* g2_bl = (const float*)d_in[19];
  const float* g2_Wr = (const float*)d_in[20];
  const float* g2_br = (const float*)d_in[21];
  const float* g2_att = (const float*)d_in[22];
  const float* g2_bias = (const float*)d_in[23];
  const float* gn2_w = (const float*)d_in[24];
  const float* gn2_b = (const float*)d_in[25];
  const float* gn2_ms = (const float*)d_in[26];
  const float* W_res = (const float*)d_in[27];
  const float* b_res = (const float*)d_in[28];
  const float* l1_Wih = (const float*)d_in[29];
  const float* l1_bih = (const float*)d_in[31];
  const float* l1_bhh = (const float*)d_in[32];
  const float* l2_Wih = (const float*)d_in[33];
  const float* l2_bih = (const float*)d_in[35];
  const float* l2_bhh = (const float*)d_in[36];
  const float* ln_w = (const float*)d_in[37];
  const float* ln_b = (const float*)d_in[38];
  const float* fc_W = (const float*)d_in[39];
  const float* fc_b = (const float*)d_in[40];
  float* out = (float*)d_out;

  const int N = in_sizes[0];
  const int E = in_sizes[3] / 2;
  const int G = out_size / 4;
  const int ET = E + N;

  char* wsb = (char*)d_ws;
  size_t off = 0;
  auto alloc = [&](size_t bytes) -> void* {
    void* p = (void*)(wsb + off);
    off = (off + bytes + 255) & ~(size_t)255;
    return p;
  };
  float* xA = (float*)alloc((size_t)N * DD * 4);               // fp32 GAT-agg output
  unsigned short* xb = (unsigned short*)alloc((size_t)N * DD * 2);  // bf16 x / x1 / x2
  int* deg = (int*)alloc((size_t)N * 4);
  int* offs = (int*)alloc((size_t)(N + 1) * 4);
  int* cursor = (int*)alloc((size_t)N * 4);
  int* partials = (int*)alloc(1024);
  int* csr = (int*)alloc((size_t)ET * 4);
  int* gstart = (int*)alloc((size_t)(G + 1) * 4);
  float* invcnt = (float*)alloc((size_t)G * 4);
  float* gsum = (float*)alloc((size_t)G * DD * 4);
  float* gsq = (float*)alloc((size_t)G * DD * 4);
  float* pooled = (float*)alloc((size_t)G * LSTMH * 4);
  float* bsum1 = (float*)alloc(ZG * 4);
  float* bsum2 = (float*)alloc(ZG * 4);
  unsigned short* wb1l = (unsigned short*)alloc((size_t)DD * DD * 2);
  unsigned short* wb1r = (unsigned short*)alloc((size_t)DD * DD * 2);
  unsigned short* wb2l = (unsigned short*)alloc((size_t)DD * DD * 2);
  unsigned short* wb2r = (unsigned short*)alloc((size_t)DD * DD * 2);
  unsigned short* wbres = (unsigned short*)alloc((size_t)DD * DD * 2);
  unsigned short* wl1b = (unsigned short*)alloc((size_t)ZG * DD * 2);
  unsigned short* wl2b = (unsigned short*)alloc((size_t)ZG * LSTMH * 2);
  size_t gatR = 3ull * N * DD * 4;
  size_t lstmR = (size_t)NCHUNK * ZG * 4 + (size_t)NCHUNK * LSTMH * 2 + (size_t)NCHUNK * LSTMH * 4;
  float* R = (float*)alloc(gatR > lstmR ? gatR : lstmR);
  (void)ws_size; (void)n_in;

  float* xl = R;
  float* xr = R + (size_t)N * DD;
  float* res = R + 2ull * N * DD;
  float* gates = R;
  unsigned short* h1b = (unsigned short*)(R + (size_t)NCHUNK * ZG);
  float* h2c = (float*)((char*)h1b + (size_t)NCHUNK * LSTMH * 2);

  hipMemsetAsync(deg, 0, (size_t)N * 4, stream);
  hipMemsetAsync(cursor, 0, (size_t)N * 4, stream);
  hipMemsetAsync(pooled, 0, (size_t)G * LSTMH * 4, stream);

  // weight conversions (tiny)
  cvt_transpose<<<cdiv_(DD * DD, 256), 256, 0, stream>>>(g1_Wl, wb1l, DD, DD);
  cvt_transpose<<<cdiv_(DD * DD, 256), 256, 0, stream>>>(g1_Wr, wb1r, DD, DD);
  cvt_transpose<<<cdiv_(DD * DD, 256), 256, 0, stream>>>(g2_Wl, wb2l, DD, DD);
  cvt_transpose<<<cdiv_(DD * DD, 256), 256, 0, stream>>>(g2_Wr, wb2r, DD, DD);
  cvt_transpose<<<cdiv_(DD * DD, 256), 256, 0, stream>>>(W_res, wbres, DD, DD);
  cvt_direct<<<cdiv_(ZG * DD, 256), 256, 0, stream>>>(l1_Wih, wl1b, ZG * DD);
  cvt_direct<<<cdiv_(ZG * LSTMH, 256), 256, 0, stream>>>(l2_Wih, wl2b, ZG * LSTMH);

  bias_sum<<<cdiv_(ZG, 256), 256, 0, stream>>>(l1_bih, l1_bhh, l2_bih, l2_bhh, bsum1, bsum2);
  graph_ranges<<<1, 128, 0, stream>>>(batch_ids, gstart, invcnt, N, G);
  embed_in<<<N, 128, 0, stream>>>(node_labels, node_types, node_feat, emb_label, emb_type,
                                  W_in, b_in, xb, N);

  // CSR by dst
  count_deg<<<cdiv_(ET, 256), 256, 0, stream>>>(edge_index, deg, E, N);
  int nb1 = cdiv_(N, 256);
  scan1<<<nb1, 256, 0, stream>>>(deg, offs, partials, N);
  scan2<<<1, 256, 0, stream>>>(partials, offs, nb1, N);
  scan3<<<nb1, 256, 0, stream>>>(offs, partials, N);
  fill_csr<<<cdiv_(ET, 256), 256, 0, stream>>>(edge_index, offs, cursor, csr, E, N);

  int mb = cdiv_(N, 128);
  // ---- GAT layer 1 ----
  gemm_bf16<<<dim3(1, mb), 256, 0, stream>>>(xb, wb1l, g1_bl, xl, N, DD, DD);
  gemm_bf16<<<dim3(1, mb), 256, 0, stream>>>(xb, wb1r, g1_br, xr, N, DD, DD);
  gat_agg<<<cdiv_(N, 4), 256, 0, stream>>>(xl, xr, csr, offs, g1_att, g1_bias, xA, N);
  hipMemsetAsync(gsum, 0, (size_t)G * DD * 8, stream);  // gsum+gsq contiguous
  gn_stats2<<<cdiv_(N, 128), 256, 0, stream>>>(xA, batch_ids, gsum, gsq, N);
  gn_apply<false><<<cdiv_(N * DD, 256), 256, 0, stream>>>(xA, xb, nullptr, batch_ids, gsum, gsq,
                                                          invcnt, gn1_w, gn1_b, gn1_ms, N);
  // ---- GAT layer 2 + residual ----
  gemm_bf16<<<dim3(1, mb), 256, 0, stream>>>(xb, wb2l, g2_bl, xl, N, DD, DD);
  gemm_bf16<<<dim3(1, mb), 256, 0, stream>>>(xb, wb2r, g2_br, xr, N, DD, DD);
  gemm_bf16<<<dim3(1, mb), 256, 0, stream>>>(xb, wbres, b_res, res, N, DD, DD);
  gat_agg<<<cdiv_(N, 4), 256, 0, stream>>>(xl, xr, csr, offs, g2_att, g2_bias, xA, N);
  hipMemsetAsync(gsum, 0, (size_t)G * DD * 8, stream);
  gn_stats2<<<cdiv_(N, 128), 256, 0, stream>>>(xA, batch_ids, gsum, gsq, N);
  gn_apply<true><<<cdiv_(N * DD, 256), 256, 0, stream>>>(xA, xb, res, batch_ids, gsum, gsq,
                                                         invcnt, gn2_w, gn2_b, gn2_ms, N);
  // ---- LSTM x2 + LN + pool (chunked over rows) ----
  for (int base = 0; base < N; base += NCHUNK) {
    int rows = N - base < NCHUNK ? N - base : NCHUNK;
    gemm_bf16<<<dim3(ZG / 128, cdiv_(rows, 128)), 256, 0, stream>>>(
        xb + (size_t)base * DD, wl1b, bsum1, gates, rows, DD, ZG);
    lstm_act_bf<<<cdiv_(rows * LSTMH, 256), 256, 0, stream>>>(gates, h1b, rows);
    gemm_bf16<<<dim3(ZG / 128, cdiv_(rows, 128)), 256, 0, stream>>>(
        h1b, wl2b, bsum2, gates, rows, LSTMH, ZG);
    lstm_act_f<<<cdiv_(rows * LSTMH, 256), 256, 0, stream>>>(gates, h2c, rows);
    ln_pool<<<rows, 256, 0, stream>>>(h2c, batch_ids, ln_w, ln_b, invcnt, pooled, base, rows);
  }
  fc_lsm<<<G, 64, 0, stream>>>(pooled, fc_W, fc_b, out);
}

// Round 3
// 635.441 us; speedup vs baseline: 3.3142x; 1.6716x over previous
//
#include <hip/hip_runtime.h>
#include <cstdint>
#include <cstddef>

#define DD 128
#define LSTMH 256
#define ZG 1024

typedef __attribute__((ext_vector_type(8))) short short8v;
typedef __attribute__((ext_vector_type(4))) float float4v;

static inline int cdiv_(int a, int b) { return (a + b - 1) / b; }

__device__ __forceinline__ float sigm_(float x) { return 1.f / (1.f + __expf(-x)); }
__device__ __forceinline__ float tanh_(float x) {
  float e = __expf(-2.f * fabsf(x));
  float r = (1.f - e) / (1.f + e);
  return copysignf(r, x);
}

__device__ __forceinline__ unsigned short f2bf(float f) {
  uint32_t u = __float_as_uint(f);
  u += 0x7fffu + ((u >> 16) & 1u);
  return (unsigned short)(u >> 16);
}
__device__ __forceinline__ float bflo(uint32_t u) { return __uint_as_float(u << 16); }
__device__ __forceinline__ float bfhi(uint32_t u) { return __uint_as_float(u & 0xffff0000u); }
__device__ __forceinline__ float bfu(unsigned short u) { return __uint_as_float((uint32_t)u << 16); }

// ---------------- weight conversion ----------------
__global__ void cvt_direct(const float* __restrict__ W, unsigned short* __restrict__ o, int n) {
  int i = blockIdx.x * 256 + threadIdx.x;
  if (i < n) o[i] = f2bf(W[i]);
}

// W[K][M] row-major -> o[M][K] bf16
__global__ void cvt_transpose(const float* __restrict__ W, unsigned short* __restrict__ o,
                              int K, int M) {
  int i = blockIdx.x * 256 + threadIdx.x;
  if (i >= K * M) return;
  int m = i / K, k = i - m * K;
  o[i] = f2bf(W[(size_t)k * M + m]);
}

// bias concat + lstm bias sums
__global__ void prep_small(const float* g1bl, const float* g1br, const float* g2bl,
                           const float* g2br, const float* bres, const float* l1bih,
                           const float* l1bhh, const float* l2bih, const float* l2bhh,
                           float* bcat1, float* bcat2, float* bsum1, float* bsum2) {
  int t = blockIdx.x * 256 + threadIdx.x;
  if (t < 256) bcat1[t] = t < 128 ? g1bl[t] : g1br[t - 128];
  if (t < 384) bcat2[t] = t < 128 ? g2bl[t] : (t < 256 ? g2br[t - 128] : bres[t - 256]);
  if (t < ZG) { bsum1[t] = l1bih[t] + l1bhh[t]; bsum2[t] = l2bih[t] + l2bhh[t]; }
}

// ---------------- input embedding + W_in GEMV (K=33) -> bf16 ----------------
__global__ __launch_bounds__(128) void embed_in(
    const int* __restrict__ labels, const int* __restrict__ types,
    const float* __restrict__ nf, const float* __restrict__ embL,
    const float* __restrict__ embT, const float* __restrict__ W,
    const float* __restrict__ b, unsigned short* __restrict__ x, int N) {
  int n = blockIdx.x;
  if (n >= N) return;
  int t = threadIdx.x;
  __shared__ float f[33];
  if (t < 16) f[t] = embL[labels[n] * 16 + t];
  else if (t < 32) f[t] = embT[types[n] * 16 + (t - 16)];
  else if (t == 32) f[32] = nf[n];
  __syncthreads();
  float acc = b[t];
#pragma unroll
  for (int k = 0; k < 33; ++k) acc += f[k] * W[k * DD + t];
  x[(size_t)n * DD + t] = f2bf(acc);
}

// ---------------- CSR build ----------------
__global__ void count_deg(const int* __restrict__ ei, int* __restrict__ deg, int E_, int N_) {
  int i = blockIdx.x * 256 + threadIdx.x;
  if (i < E_) atomicAdd(&deg[ei[E_ + i]], 1);
  else if (i < E_ + N_) atomicAdd(&deg[i - E_], 1);
}

__global__ __launch_bounds__(256) void scan1(const int* __restrict__ deg, int* __restrict__ offs,
                                             int* __restrict__ partials, int N_) {
  __shared__ int buf[2][256];
  int tid = threadIdx.x;
  int i = blockIdx.x * 256 + tid;
  int v = (i < N_) ? deg[i] : 0;
  buf[0][tid] = v;
  __syncthreads();
  int cur = 0;
#pragma unroll
  for (int d = 1; d < 256; d <<= 1) {
    int xv = buf[cur][tid];
    if (tid >= d) xv += buf[cur][tid - d];
    buf[cur ^ 1][tid] = xv;
    cur ^= 1;
    __syncthreads();
  }
  int incl = buf[cur][tid];
  if (i < N_) offs[i] = incl - v;
  if (tid == 255) partials[blockIdx.x] = incl;
}

__global__ __launch_bounds__(256) void scan2(int* __restrict__ partials, int* __restrict__ offs,
                                             int nb, int N_) {
  __shared__ int buf[2][256];
  int tid = threadIdx.x;
  int v = (tid < nb) ? partials[tid] : 0;
  buf[0][tid] = v;
  __syncthreads();
  int cur = 0;
#pragma unroll
  for (int d = 1; d < 256; d <<= 1) {
    int xv = buf[cur][tid];
    if (tid >= d) xv += buf[cur][tid - d];
    buf[cur ^ 1][tid] = xv;
    cur ^= 1;
    __syncthreads();
  }
  int incl = buf[cur][tid];
  if (tid < nb) partials[tid] = incl - v;
  if (tid == 255) offs[N_] = incl;
}

__global__ void scan3(int* __restrict__ offs, const int* __restrict__ partials, int N_) {
  int i = blockIdx.x * 256 + threadIdx.x;
  if (i < N_) offs[i] += partials[blockIdx.x];
}

__global__ void fill_csr(const int* __restrict__ ei, const int* __restrict__ offs,
                         int* __restrict__ cursor, int* __restrict__ csr, int E_, int N_) {
  int i = blockIdx.x * 256 + threadIdx.x;
  int s, d;
  if (i < E_) { s = ei[i]; d = ei[E_ + i]; }
  else if (i < E_ + N_) { s = d = i - E_; }
  else return;
  int pos = offs[d] + atomicAdd(&cursor[d], 1);
  csr[pos] = s;
}

// ---------------- graph ranges ----------------
__global__ void graph_ranges(const int* __restrict__ bids, int* __restrict__ gstart,
                             float* __restrict__ invcnt, int N_, int G_) {
  int t = threadIdx.x;
  if (t <= G_) {
    int lo = 0, hi = N_;
    while (lo < hi) { int mid = (lo + hi) >> 1; if (bids[mid] < t) lo = mid + 1; else hi = mid; }
    gstart[t] = lo;
  }
  __syncthreads();
  if (t < G_) {
    int c = gstart[t + 1] - gstart[t];
    invcnt[t] = (c > 0) ? 1.f / (float)c : 0.f;
  }
}

// ---------------- bf16 MFMA GEMM: C[M,Ncols] bf16 = A[M,K]bf16 @ B'[Ncols,K]^T + bias
// grid (Ncols/128, cdiv(M,128)), block 256 (4 waves, 2x2, each 64x64 output)
__global__ __launch_bounds__(256) void gemm_bf16(
    const unsigned short* __restrict__ A, const unsigned short* __restrict__ Bp,
    const float* __restrict__ bias, unsigned short* __restrict__ C, int M, int K, int Ncols) {
  __shared__ unsigned short As[128 * 40];
  __shared__ unsigned short Bs[128 * 40];
  int tid = threadIdx.x;
  int lane = tid & 63;
  int wid = tid >> 6;
  int rowBase = blockIdx.y * 128, colBase = blockIdx.x * 128;
  int wr = (wid >> 1) * 64, wc = (wid & 1) * 64;
  int fr = lane & 15, fg = lane >> 4;
  float4v acc[4][4];
#pragma unroll
  for (int i = 0; i < 4; ++i)
#pragma unroll
    for (int j = 0; j < 4; ++j) acc[i][j] = (float4v){0.f, 0.f, 0.f, 0.f};

  int sr = tid >> 2;
  int sc = tid & 3;
  int off_lo = (sc < 2) ? 32 * sc : 32 * sc - 56;

  for (int k0 = 0; k0 < K; k0 += 32) {
#pragma unroll
    for (int it = 0; it < 2; ++it) {
      int r = it * 64 + sr;
      uint4 va = make_uint4(0u, 0u, 0u, 0u);
      if (rowBase + r < M)
        va = *(const uint4*)(A + (size_t)(rowBase + r) * K + k0 + sc * 8);
      char* arow = (char*)(As + r * 40);
      *(uint2*)(arow + off_lo) = make_uint2(va.x, va.y);
      *(uint2*)(arow + off_lo + 16) = make_uint2(va.z, va.w);
      uint4 vb = *(const uint4*)(Bp + (size_t)(colBase + r) * K + k0 + sc * 8);
      char* brow = (char*)(Bs + r * 40);
      *(uint2*)(brow + off_lo) = make_uint2(vb.x, vb.y);
      *(uint2*)(brow + off_lo + 16) = make_uint2(vb.z, vb.w);
    }
    __syncthreads();
    short8v af[4], bfv[4];
#pragma unroll
    for (int i = 0; i < 4; ++i)
      af[i] = *(const short8v*)((const char*)As + (wr + 16 * i + fr) * 80 + fg * 16);
#pragma unroll
    for (int j = 0; j < 4; ++j)
      bfv[j] = *(const short8v*)((const char*)Bs + (wc + 16 * j + fr) * 80 + fg * 16);
#pragma unroll
    for (int i = 0; i < 4; ++i)
#pragma unroll
      for (int j = 0; j < 4; ++j)
        acc[i][j] = __builtin_amdgcn_mfma_f32_16x16x32_bf16(af[i], bfv[j], acc[i][j], 0, 0, 0);
    __syncthreads();
  }
#pragma unroll
  for (int j = 0; j < 4; ++j) {
    int gc = colBase + wc + 16 * j + fr;
    float bv = bias[gc];
#pragma unroll
    for (int i = 0; i < 4; ++i) {
      int gr0 = rowBase + wr + 16 * i + fg * 4;
#pragma unroll
      for (int rg = 0; rg < 4; ++rg) {
        int gr = gr0 + rg;
        if (gr < M) C[(size_t)gr * Ncols + gc] = f2bf(acc[i][j][rg] + bv);
      }
    }
  }
}

// ---------------- GATv2 aggregation: 1 wave/node, 2 edges in flight, bf16 gathers --------
__global__ __launch_bounds__(256) void gat_agg(
    const unsigned short* __restrict__ xlr, int stride,
    const int* __restrict__ csr, const int* __restrict__ offs,
    const float* __restrict__ att, const float* __restrict__ bias,
    float* __restrict__ out, int N) {
  int wid = (blockIdx.x * 256 + threadIdx.x) >> 6;
  if (wid >= N) return;
  int lane = threadIdx.x & 63;
  int half = lane >> 5, hl = lane & 31;
  int h = hl >> 3;
  float4 a4 = *(const float4*)&att[h * 32 + (hl & 7) * 4];
  uint2 ur = *(const uint2*)(xlr + (size_t)wid * stride + 128 + hl * 4);
  float r0 = bflo(ur.x), r1 = bfhi(ur.x), r2 = bflo(ur.y), r3 = bfhi(ur.y);
  float m = -1e30f, L = 0.f, s0 = 0.f, s1 = 0.f, s2 = 0.f, s3 = 0.f;
  int js = offs[wid], je = offs[wid + 1];
  for (int j = js + half; j < je; j += 2) {
    int s = csr[j];
    uint2 u = *(const uint2*)(xlr + (size_t)s * stride + hl * 4);
    float x0 = bflo(u.x), x1 = bfhi(u.x), x2 = bflo(u.y), x3 = bfhi(u.y);
    float v0 = r0 + x0; v0 = v0 > 0.f ? v0 : 0.2f * v0;
    float v1 = r1 + x1; v1 = v1 > 0.f ? v1 : 0.2f * v1;
    float v2 = r2 + x2; v2 = v2 > 0.f ? v2 : 0.2f * v2;
    float v3 = r3 + x3; v3 = v3 > 0.f ? v3 : 0.2f * v3;
    float p = a4.x * v0 + a4.y * v1 + a4.z * v2 + a4.w * v3;
    p += __shfl_xor(p, 1); p += __shfl_xor(p, 2); p += __shfl_xor(p, 4);
    float mn = fmaxf(m, p);
    float ea = __expf(p - mn);
    float es = __expf(m - mn);
    L = L * es + ea;
    s0 = s0 * es + ea * x0;
    s1 = s1 * es + ea * x1;
    s2 = s2 * es + ea * x2;
    s3 = s3 * es + ea * x3;
    m = mn;
  }
  // merge the two half-wave online-softmax states
  float mo = __shfl_xor(m, 32), Lo = __shfl_xor(L, 32);
  float t0 = __shfl_xor(s0, 32), t1 = __shfl_xor(s1, 32);
  float t2 = __shfl_xor(s2, 32), t3 = __shfl_xor(s3, 32);
  float mn = fmaxf(m, mo);
  float e0 = __expf(m - mn), e1 = __expf(mo - mn);
  L = L * e0 + Lo * e1;
  s0 = s0 * e0 + t0 * e1;
  s1 = s1 * e0 + t1 * e1;
  s2 = s2 * e0 + t2 * e1;
  s3 = s3 * e0 + t3 * e1;
  if (half == 0) {
    float inv = 1.f / L;
    float4 b4 = *(const float4*)&bias[hl * 4];
    float4 o4;
    o4.x = s0 * inv + b4.x;
    o4.y = s1 * inv + b4.y;
    o4.z = s2 * inv + b4.z;
    o4.w = s3 * inv + b4.w;
    *(float4*)&out[(size_t)wid * DD + hl * 4] = o4;
  }
}

// ---------------- GraphNorm stats ----------------
__global__ __launch_bounds__(256) void gn_stats2(const float* __restrict__ x,
                                                 const int* __restrict__ bids,
                                                 float* __restrict__ gsum,
                                                 float* __restrict__ gsq, int N) {
  int base = blockIdx.x * 128;
  int ch = threadIdx.x & 127;
  int sub = threadIdx.x >> 7;
  int end = base + 128 < N ? base + 128 : N;
  int curg = -1;
  float s = 0.f, q = 0.f;
  for (int r = base + sub; r < end; r += 2) {
    int g = bids[r];
    if (g != curg) {
      if (curg >= 0) {
        atomicAdd(&gsum[curg * DD + ch], s);
        atomicAdd(&gsq[curg * DD + ch], q);
      }
      curg = g; s = 0.f; q = 0.f;
    }
    float v = x[(size_t)r * DD + ch];
    s += v; q += v * v;
  }
  if (curg >= 0) {
    atomicAdd(&gsum[curg * DD + ch], s);
    atomicAdd(&gsq[curg * DD + ch], q);
  }
}

// ---------------- GraphNorm apply + ELU (+residual bf16) -> bf16 ----------------
template <bool ADDRES>
__global__ void gn_apply(const float* __restrict__ xin, unsigned short* __restrict__ xout,
                         const unsigned short* __restrict__ res, int resStride,
                         const int* __restrict__ bids, const float* __restrict__ gsum,
                         const float* __restrict__ gsq, const float* __restrict__ invcnt,
                         const float* __restrict__ w, const float* __restrict__ b,
                         const float* __restrict__ ms, int N) {
  int idx = blockIdx.x * 256 + threadIdx.x;
  if (idx >= N * DD) return;
  int n = idx >> 7, ch = idx & 127;
  int g = bids[n];
  float ic = invcnt[g];
  float mean = gsum[g * DD + ch] * ic;
  float ex2 = gsq[g * DD + ch] * ic;
  float mm = mean * ms[ch];
  float var = ex2 - mm * (2.f * mean - mm);
  float v = (xin[idx] - mm) * rsqrtf(var + 1e-5f) * w[ch] + b[ch];
  if (ADDRES) v += bfu(res[(size_t)n * resStride + ch]);
  v = v > 0.f ? v : (__expf(v) - 1.f);
  xout[idx] = f2bf(v);
}

// ---------------- fused LSTM step: h = sig(o)*tanh(sig(i)*tanh(g)), f-gate dead ----------
// A[M][KDIM] bf16, Bp[1024][KDIM] bf16 (gate-major rows: i 0-255, f 256-511, g 512-767,
// o 768-1023), bsum[1024] f32. Block: 256 rows x 32 h-channels (96 gate cols i,g,o).
// Grid (LSTMH/32, cdiv(M,256)). 4 waves, each 64 rows x 96 cols.
template <int KDIM>
__global__ __launch_bounds__(256) void lstm_fused(
    const unsigned short* __restrict__ A, const unsigned short* __restrict__ Bp,
    const float* __restrict__ bsum, unsigned short* __restrict__ H, int M) {
  __shared__ unsigned short As[256 * 40];
  __shared__ unsigned short Bs[96 * 40];
  int tid = threadIdx.x;
  int lane = tid & 63;
  int wid = tid >> 6;
  int rowBase = blockIdx.y * 256;
  int hc0 = blockIdx.x * 32;
  int wy = wid * 64;
  int fr = lane & 15, fg = lane >> 4;
  float4v acc[4][6];
#pragma unroll
  for (int i = 0; i < 4; ++i)
#pragma unroll
    for (int j = 0; j < 6; ++j) acc[i][j] = (float4v){0.f, 0.f, 0.f, 0.f};

  int sr = tid >> 2;
  int sc = tid & 3;
  int off_lo = (sc < 2) ? 32 * sc : 32 * sc - 56;

  for (int k0 = 0; k0 < KDIM; k0 += 32) {
#pragma unroll
    for (int it = 0; it < 4; ++it) {
      int r = it * 64 + sr;
      uint4 va = make_uint4(0u, 0u, 0u, 0u);
      if (rowBase + r < M)
        va = *(const uint4*)(A + (size_t)(rowBase + r) * KDIM + k0 + sc * 8);
      char* arow = (char*)(As + r * 40);
      *(uint2*)(arow + off_lo) = make_uint2(va.x, va.y);
      *(uint2*)(arow + off_lo + 16) = make_uint2(va.z, va.w);
    }
#pragma unroll
    for (int it = 0; it < 2; ++it) {
      int li = it * 256 + tid;
      if (li < 384) {
        int r = li >> 2, bc = li & 3;
        int q = r >> 5;
        int qmap = (q == 0) ? 0 : (q == 1 ? 2 : 3);
        int grow = qmap * 256 + hc0 + (r & 31);
        uint4 vb = *(const uint4*)(Bp + (size_t)grow * KDIM + k0 + bc * 8);
        int blo = (bc < 2) ? 32 * bc : 32 * bc - 56;
        char* brow = (char*)(Bs + r * 40);
        *(uint2*)(brow + blo) = make_uint2(vb.x, vb.y);
        *(uint2*)(brow + blo + 16) = make_uint2(vb.z, vb.w);
      }
    }
    __syncthreads();
    short8v af[4], bfv[6];
#pragma unroll
    for (int i = 0; i < 4; ++i)
      af[i] = *(const short8v*)((const char*)As + (wy + 16 * i + fr) * 80 + fg * 16);
#pragma unroll
    for (int j = 0; j < 6; ++j)
      bfv[j] = *(const short8v*)((const char*)Bs + (16 * j + fr) * 80 + fg * 16);
#pragma unroll
    for (int i = 0; i < 4; ++i)
#pragma unroll
      for (int j = 0; j < 6; ++j)
        acc[i][j] = __builtin_amdgcn_mfma_f32_16x16x32_bf16(af[i], bfv[j], acc[i][j], 0, 0, 0);
    __syncthreads();
  }
  // epilogue: lane holds i,g,o for channels hc0+fr (cg=0) and hc0+16+fr (cg=1)
#pragma unroll
  for (int cg = 0; cg < 2; ++cg) {
    int hc = hc0 + fr + 16 * cg;
    float bi = bsum[hc], bg = bsum[512 + hc], bo = bsum[768 + hc];
#pragma unroll
    for (int i = 0; i < 4; ++i) {
#pragma unroll
      for (int rg = 0; rg < 4; ++rg) {
        int row = rowBase + wy + 16 * i + fg * 4 + rg;
        if (row < M) {
          float iv = acc[i][cg][rg] + bi;
          float gv = acc[i][2 + cg][rg] + bg;
          float ov = acc[i][4 + cg][rg] + bo;
          float c = sigm_(iv) * tanh_(gv);
          H[(size_t)row * LSTMH + hc] = f2bf(sigm_(ov) * tanh_(c));
        }
      }
    }
  }
}

// ---------------- LayerNorm + mean pool: 1 wave per 8 rows, register pooling ----------
__global__ __launch_bounds__(256) void ln_pool2(
    const unsigned short* __restrict__ h2, const int* __restrict__ bids,
    const float* __restrict__ lnw, const float* __restrict__ lnb,
    const float* __restrict__ invcnt, float* __restrict__ pooled, int N) {
  int wave = (blockIdx.x * 256 + threadIdx.x) >> 6;
  int lane = threadIdx.x & 63;
  int r0 = wave * 8;
  if (r0 >= N) return;
  float4 w4 = *(const float4*)&lnw[lane * 4];
  float4 b4 = *(const float4*)&lnb[lane * 4];
  float p0 = 0.f, p1 = 0.f, p2 = 0.f, p3 = 0.f;
  int curg = bids[r0];
  int rend = r0 + 8 < N ? r0 + 8 : N;
  for (int r = r0; r < rend; ++r) {
    int g = bids[r];
    if (g != curg) {
      float ic = invcnt[curg];
      atomicAdd(&pooled[curg * LSTMH + lane * 4 + 0], p0 * ic);
      atomicAdd(&pooled[curg * LSTMH + lane * 4 + 1], p1 * ic);
      atomicAdd(&pooled[curg * LSTMH + lane * 4 + 2], p2 * ic);
      atomicAdd(&pooled[curg * LSTMH + lane * 4 + 3], p3 * ic);
      p0 = p1 = p2 = p3 = 0.f;
      curg = g;
    }
    uint2 u = *(const uint2*)(h2 + (size_t)r * LSTMH + lane * 4);
    float v0 = bflo(u.x), v1 = bfhi(u.x), v2 = bflo(u.y), v3 = bfhi(u.y);
    float s = v0 + v1 + v2 + v3;
    float q = v0 * v0 + v1 * v1 + v2 * v2 + v3 * v3;
#pragma unroll
    for (int d = 1; d < 64; d <<= 1) { s += __shfl_xor(s, d); q += __shfl_xor(q, d); }
    float mu = s * (1.f / 256.f);
    float var = q * (1.f / 256.f) - mu * mu;
    float rs = rsqrtf(var + 1e-5f);
    p0 += w4.x * (v0 - mu) * rs + b4.x;
    p1 += w4.y * (v1 - mu) * rs + b4.y;
    p2 += w4.z * (v2 - mu) * rs + b4.z;
    p3 += w4.w * (v3 - mu) * rs + b4.w;
  }
  float ic = invcnt[curg];
  atomicAdd(&pooled[curg * LSTMH + lane * 4 + 0], p0 * ic);
  atomicAdd(&pooled[curg * LSTMH + lane * 4 + 1], p1 * ic);
  atomicAdd(&pooled[curg * LSTMH + lane * 4 + 2], p2 * ic);
  atomicAdd(&pooled[curg * LSTMH + lane * 4 + 3], p3 * ic);
}

// ---------------- FC + log_softmax ----------------
__global__ __launch_bounds__(64) void fc_lsm(const float* __restrict__ pooled,
                                             const float* __restrict__ W,
                                             const float* __restrict__ b, float* __restrict__ out) {
  int g = blockIdx.x;
  int t = threadIdx.x;
  float l0 = 0.f, l1 = 0.f, l2 = 0.f, l3 = 0.f;
  for (int k = t; k < LSTMH; k += 64) {
    float p = pooled[g * LSTMH + k];
    l0 += p * W[k * 4 + 0];
    l1 += p * W[k * 4 + 1];
    l2 += p * W[k * 4 + 2];
    l3 += p * W[k * 4 + 3];
  }
#pragma unroll
  for (int d = 1; d < 64; d <<= 1) {
    l0 += __shfl_xor(l0, d); l1 += __shfl_xor(l1, d);
    l2 += __shfl_xor(l2, d); l3 += __shfl_xor(l3, d);
  }
  if (t == 0) {
    float z[4] = {l0 + b[0], l1 + b[1], l2 + b[2], l3 + b[3]};
    float mx = fmaxf(fmaxf(z[0], z[1]), fmaxf(z[2], z[3]));
    float sum = __expf(z[0] - mx) + __expf(z[1] - mx) + __expf(z[2] - mx) + __expf(z[3] - mx);
    float ls = logf(sum);
#pragma unroll
    for (int o = 0; o < 4; ++o) out[g * 4 + o] = z[o] - mx - ls;
  }
}

// ---------------- host launch ----------------
extern "C" void kernel_launch(void* const* d_in, const int* in_sizes, int n_in,
                              void* d_out, int out_size, void* d_ws, size_t ws_size,
                              hipStream_t stream) {
  const int* node_labels = (const int*)d_in[0];
  const int* node_types = (const int*)d_in[1];
  const float* node_feat = (const float*)d_in[2];
  const int* edge_index = (const int*)d_in[3];
  const int* batch_ids = (const int*)d_in[4];
  const float* emb_label = (const float*)d_in[5];
  const float* emb_type = (const float*)d_in[6];
  const float* W_in = (const float*)d_in[7];
  const float* b_in = (const float*)d_in[8];
  const float* g1_Wl = (const float*)d_in[9];
  const float* g1_bl = (const float*)d_in[10];
  const float* g1_Wr = (const float*)d_in[11];
  const float* g1_br = (const float*)d_in[12];
  const float* g1_att = (const float*)d_in[13];
  const float* g1_bias = (const float*)d_in[14];
  const float* gn1_w = (const float*)d_in[15];
  const float* gn1_b = (const float*)d_in[16];
  const float* gn1_ms = (const float*)d_in[17];
  const float* g2_Wl = (const float*)d_in[18];
  const float* g2_bl = (const float*)d_in[19];
  const float* g2_Wr = (const float*)d_in[20];
  const float* g2_br = (const float*)d_in[21];
  const float* g2_att = (const float*)d_in[22];
  const float* g2_bias = (const float*)d_in[23];
  const float* gn2_w = (const float*)d_in[24];
  const float* gn2_b = (const float*)d_in[25];
  const float* gn2_ms = (const float*)d_in[26];
  const float* W_res = (const float*)d_in[27];
  const float* b_res = (const float*)d_in[28];
  const float* l1_Wih = (const float*)d_in[29];
  const float* l1_bih = (const float*)d_in[31];
  const float* l1_bhh = (const float*)d_in[32];
  const float* l2_Wih = (const float*)d_in[33];
  const float* l2_bih = (const float*)d_in[35];
  const float* l2_bhh = (const float*)d_in[36];
  const float* ln_w = (const float*)d_in[37];
  const float* ln_b = (const float*)d_in[38];
  const float* fc_W = (const float*)d_in[39];
  const float* fc_b = (const float*)d_in[40];
  float* out = (float*)d_out;

  const int N = in_sizes[0];
  const int E = in_sizes[3] / 2;
  const int G = out_size / 4;
  const int ET = E + N;

  char* wsb = (char*)d_ws;
  size_t off = 0;
  auto alloc = [&](size_t bytes) -> void* {
    void* p = (void*)(wsb + off);
    off = (off + bytes + 255) & ~(size_t)255;
    return p;
  };
  float* xA = (float*)alloc((size_t)N * DD * 4);                    // gat out f32; later h2 bf16
  unsigned short* xb = (unsigned short*)alloc((size_t)N * DD * 2);  // bf16 x / x1 / x2
  unsigned short* xlr = (unsigned short*)alloc((size_t)N * 384 * 2);  // xl|xr(|res); later h1
  int* deg = (int*)alloc((size_t)N * 4);
  int* offs = (int*)alloc((size_t)(N + 1) * 4);
  int* cursor = (int*)alloc((size_t)N * 4);
  int* partials = (int*)alloc(1024);
  int* csr = (int*)alloc((size_t)ET * 4);
  int* gstart = (int*)alloc((size_t)(G + 1) * 4);
  float* invcnt = (float*)alloc((size_t)G * 4);
  float* gsum = (float*)alloc((size_t)G * DD * 4);
  float* gsq = (float*)alloc((size_t)G * DD * 4);
  float* pooled = (float*)alloc((size_t)G * LSTMH * 4);
  float* bcat1 = (float*)alloc(256 * 4);
  float* bcat2 = (float*)alloc(384 * 4);
  float* bsum1 = (float*)alloc(ZG * 4);
  float* bsum2 = (float*)alloc(ZG * 4);
  unsigned short* wcat1 = (unsigned short*)alloc((size_t)256 * DD * 2);
  unsigned short* wcat2 = (unsigned short*)alloc((size_t)384 * DD * 2);
  unsigned short* wl1b = (unsigned short*)alloc((size_t)ZG * DD * 2);
  unsigned short* wl2b = (unsigned short*)alloc((size_t)ZG * LSTMH * 2);
  (void)ws_size; (void)n_in;

  unsigned short* h1 = xlr;              // [N][256] bf16, written after xlr dead
  unsigned short* h2 = (unsigned short*)xA;  // [N][256] bf16, written after xA dead

  hipMemsetAsync(deg, 0, (size_t)N * 4, stream);
  hipMemsetAsync(cursor, 0, (size_t)N * 4, stream);
  hipMemsetAsync(pooled, 0, (size_t)G * LSTMH * 4, stream);

  // weight prep
  cvt_transpose<<<cdiv_(DD * DD, 256), 256, 0, stream>>>(g1_Wl, wcat1, DD, DD);
  cvt_transpose<<<cdiv_(DD * DD, 256), 256, 0, stream>>>(g1_Wr, wcat1 + DD * DD, DD, DD);
  cvt_transpose<<<cdiv_(DD * DD, 256), 256, 0, stream>>>(g2_Wl, wcat2, DD, DD);
  cvt_transpose<<<cdiv_(DD * DD, 256), 256, 0, stream>>>(g2_Wr, wcat2 + DD * DD, DD, DD);
  cvt_transpose<<<cdiv_(DD * DD, 256), 256, 0, stream>>>(W_res, wcat2 + 2 * DD * DD, DD, DD);
  cvt_direct<<<cdiv_(ZG * DD, 256), 256, 0, stream>>>(l1_Wih, wl1b, ZG * DD);
  cvt_direct<<<cdiv_(ZG * LSTMH, 256), 256, 0, stream>>>(l2_Wih, wl2b, ZG * LSTMH);
  prep_small<<<4, 256, 0, stream>>>(g1_bl, g1_br, g2_bl, g2_br, b_res, l1_bih, l1_bhh,
                                    l2_bih, l2_bhh, bcat1, bcat2, bsum1, bsum2);

  graph_ranges<<<1, 128, 0, stream>>>(batch_ids, gstart, invcnt, N, G);
  embed_in<<<N, 128, 0, stream>>>(node_labels, node_types, node_feat, emb_label, emb_type,
                                  W_in, b_in, xb, N);

  // CSR by dst
  count_deg<<<cdiv_(ET, 256), 256, 0, stream>>>(edge_index, deg, E, N);
  int nb1 = cdiv_(N, 256);
  scan1<<<nb1, 256, 0, stream>>>(deg, offs, partials, N);
  scan2<<<1, 256, 0, stream>>>(partials, offs, nb1, N);
  scan3<<<nb1, 256, 0, stream>>>(offs, partials, N);
  fill_csr<<<cdiv_(ET, 256), 256, 0, stream>>>(edge_index, offs, cursor, csr, E, N);

  int mb = cdiv_(N, 128);
  // ---- GAT layer 1: [xl|xr] in one GEMM ----
  gemm_bf16<<<dim3(2, mb), 256, 0, stream>>>(xb, wcat1, bcat1, xlr, N, DD, 256);
  gat_agg<<<cdiv_(N, 4), 256, 0, stream>>>(xlr, 256, csr, offs, g1_att, g1_bias, xA, N);
  hipMemsetAsync(gsum, 0, (size_t)G * DD * 8, stream);  // gsum+gsq contiguous
  gn_stats2<<<cdiv_(N, 128), 256, 0, stream>>>(xA, batch_ids, gsum, gsq, N);
  gn_apply<false><<<cdiv_(N * DD, 256), 256, 0, stream>>>(
      xA, xb, nullptr, 0, batch_ids, gsum, gsq, invcnt, gn1_w, gn1_b, gn1_ms, N);
  // ---- GAT layer 2: [xl|xr|res] in one GEMM ----
  gemm_bf16<<<dim3(3, mb), 256, 0, stream>>>(xb, wcat2, bcat2, xlr, N, DD, 384);
  gat_agg<<<cdiv_(N, 4), 256, 0, stream>>>(xlr, 384, csr, offs, g2_att, g2_bias, xA, N);
  hipMemsetAsync(gsum, 0, (size_t)G * DD * 8, stream);
  gn_stats2<<<cdiv_(N, 128), 256, 0, stream>>>(xA, batch_ids, gsum, gsq, N);
  gn_apply<true><<<cdiv_(N * DD, 256), 256, 0, stream>>>(
      xA, xb, xlr + 256, 384, batch_ids, gsum, gsq, invcnt, gn2_w, gn2_b, gn2_ms, N);
  // ---- fused LSTM x2 ----
  lstm_fused<DD><<<dim3(LSTMH / 32, cdiv_(N, 256)), 256, 0, stream>>>(xb, wl1b, bsum1, h1, N);
  lstm_fused<LSTMH><<<dim3(LSTMH / 32, cdiv_(N, 256)), 256, 0, stream>>>(h1, wl2b, bsum2, h2, N);
  // ---- LN + mean pool + FC ----
  ln_pool2<<<cdiv_(N, 32), 256, 0, stream>>>(h2, batch_ids, ln_w, ln_b, invcnt, pooled, N);
  fc_lsm<<<G, 64, 0, stream>>>(pooled, fc_W, fc_b, out);
}